// Round 11
// baseline (1791.795 us; speedup 1.0000x reference)
//
#include <hip/hip_runtime.h>

#define T_STEPS 1000
#define DT 0.1f
#define HIDDEN 128
#define N_AGENTS 1024

typedef float v2f __attribute__((ext_vector_type(2)));

// tanh(x) = 1 - 2/(exp(2x)+1); exact at +/-inf, ~1e-7 rel error.
__device__ __forceinline__ float tanh_fast(float x) {
    float e = __expf(2.0f * x);
    return 1.0f - 2.0f * __builtin_amdgcn_rcpf(e + 1.0f);
}

// Opaque 8B load (R13-R18 proven residency mechanism).
__device__ __forceinline__ v2f opaque_load8(const float* p) {
    v2f v;
    asm volatile("global_load_dwordx2 %0, %1, off\n\ts_waitcnt vmcnt(0)"
                 : "=v"(v)
                 : "v"((unsigned long long)(uintptr_t)p)
                 : "memory");
    return v;
}

__device__ __forceinline__ float uniformf(float v) {
    return __builtin_bit_cast(float,
        __builtin_amdgcn_readfirstlane(__builtin_bit_cast(int, v)));
}

// R25: DUAL fused DPP reduction (volatile form — R29 showed non-volatile
// is neutral-to-worse; volatile also constrains liveness, which matters
// at ~490 VGPRs).
__device__ __forceinline__ void wave_sum2_dpp(float& a, float& b) {
    asm volatile(
        "s_nop 1\n\t"
        "v_add_f32_dpp %0, %0, %0 row_shr:1 row_mask:0xf bank_mask:0xf bound_ctrl:0\n\t"
        "v_add_f32_dpp %1, %1, %1 row_shr:1 row_mask:0xf bank_mask:0xf bound_ctrl:0\n\t"
        "s_nop 0\n\t"
        "v_add_f32_dpp %0, %0, %0 row_shr:2 row_mask:0xf bank_mask:0xf bound_ctrl:0\n\t"
        "v_add_f32_dpp %1, %1, %1 row_shr:2 row_mask:0xf bank_mask:0xf bound_ctrl:0\n\t"
        "s_nop 0\n\t"
        "v_add_f32_dpp %0, %0, %0 row_shr:4 row_mask:0xf bank_mask:0xf bound_ctrl:0\n\t"
        "v_add_f32_dpp %1, %1, %1 row_shr:4 row_mask:0xf bank_mask:0xf bound_ctrl:0\n\t"
        "s_nop 0\n\t"
        "v_add_f32_dpp %0, %0, %0 row_shr:8 row_mask:0xf bank_mask:0xf bound_ctrl:0\n\t"
        "v_add_f32_dpp %1, %1, %1 row_shr:8 row_mask:0xf bank_mask:0xf bound_ctrl:0\n\t"
        "s_nop 0\n\t"
        "v_add_f32_dpp %0, %0, %0 row_bcast:15 row_mask:0xa bank_mask:0xf bound_ctrl:0\n\t"
        "v_add_f32_dpp %1, %1, %1 row_bcast:15 row_mask:0xa bank_mask:0xf bound_ctrl:0\n\t"
        "s_nop 0\n\t"
        "v_add_f32_dpp %0, %0, %0 row_bcast:31 row_mask:0xc bank_mask:0xf bound_ctrl:0\n\t"
        "v_add_f32_dpp %1, %1, %1 row_bcast:31 row_mask:0xc bank_mask:0xf bound_ctrl:0\n\t"
        "s_nop 1"
        : "+v"(a), "+v"(b));
}

// Pre-pack W1 into component-paired layout (R14-R18 verified).
__global__ void pack_kernel(const float* __restrict__ W1,
                            float* __restrict__ pw) {
    const int row = blockIdx.x;     // 128
    const int a   = threadIdx.x;    // 32
    const float* rp = W1 + row * 128;
    float* out = pw + row * 128;
    out[2*a]          = rp[3*a];
    out[2*a + 1]      = rp[3*a + 1];
    out[64 + 2*a]     = rp[3*a + 2];
    out[64 + 2*a + 1] = rp[96 + a];
}

// R30: SINGLE-WAVE MERGE. One 64-lane wave per agent executes BOTH the
// old consumer (ages 0-15) and producer (ages 16-31) code paths with
// identical per-accumulator operand orders:
//  - consumer code verbatim (R25/R27 form); pl read from a 16-entry
//    REGISTER ring instead of part1 LDS (same values: shipped sums are
//    final at ship time; WAR/RAW verified for every index).
//  - producer batches repositioned to run right after the 4-step group
//    producing their inputs (taps only order among themselves; total
//    h1 sequence 0,1,2,3,0,... unchanged); inputs read from the es
//    register buffers (identical values; removes the cursed LDS state
//    path entirely). Ship n->pl indices: n=0->9..12, 1->13,14,15,0,
//    2->1..4, 3->5..8.
//  - group->buffer alternation A,B,A,B per window; h0_batch uses the
//    just-filled buffer, h1_batch the other (2-group lag).
// No barriers, no LDS, 1 wave/SIMD (512-VGPR budget; need ~490).
// Eliminates the ~590 cyc/step of consumer-stall x producer-barrier idle.
__global__ __launch_bounds__(64)
__attribute__((amdgpu_waves_per_eu(1, 1)))
void sim_kernel(const float* __restrict__ target_pos,
                const float* __restrict__ logsigma,
                const float* __restrict__ x_inits,
                const float* __restrict__ pw,
                const float* __restrict__ b1,
                const float* __restrict__ W2,
                const float* __restrict__ b2,
                float2* __restrict__ ws) {
    const int agent = blockIdx.x;
    const int lane  = threadIdx.x;   // 0..63 — single wave
    const int rowA = lane;
    const int rowB = lane + 64;

    const float tx0 = uniformf(target_pos[0]), ty0 = uniformf(target_pos[1]);
    const float tx1 = uniformf(target_pos[2]), ty1 = uniformf(target_pos[3]);
    const float tx2 = uniformf(target_pos[4]), ty2 = uniformf(target_pos[5]);
    const float is0 = uniformf(1.0f / expf(logsigma[0]));
    const float is1 = uniformf(1.0f / expf(logsigma[1]));
    const float is2 = uniformf(1.0f / expf(logsigma[2]));

    // ALL 32 ages: 0..15 = old consumer set, 16..31 = old producer set.
    v2f WxyA[32], WzcA[32], WxyB[32], WzcB[32];
    {
        const float* baseA = pw + rowA * 128;
        const float* baseB = pw + rowB * 128;
        #pragma unroll
        for (int i = 0; i < 32; ++i) {
            WxyA[i] = opaque_load8(baseA + 2 * i);
            WzcA[i] = opaque_load8(baseA + 64 + 2 * i);
            WxyB[i] = opaque_load8(baseB + 2 * i);
            WzcB[i] = opaque_load8(baseB + 64 + 2 * i);
        }
    }
    const float b1A = b1[rowA], b1B = b1[rowB];
    const float w20A = W2[rowA], w20B = W2[rowB];
    const float w21A = W2[HIDDEN + rowA], w21B = W2[HIDDEN + rowB];
    const float b2x = uniformf(b2[0]), b2y = uniformf(b2[1]);

    auto conc = [&](float px, float py) {
        float dx0 = px - tx0, dy0 = py - ty0;
        float dx1 = px - tx1, dy1 = py - ty1;
        float dx2 = px - tx2, dy2 = py - ty2;
        float cc  = is0 * __expf(-(dx0*dx0 + dy0*dy0) * is0);
        cc       += is1 * __expf(-(dx1*dx1 + dy1*dy1) * is1);
        cc       += is2 * __expf(-(dx2*dx2 + dy2*dy2) * is2);
        return cc;
    };

    float x  = uniformf(x_inits[3 * agent]);
    float y  = uniformf(x_inits[3 * agent + 1]);
    float th = uniformf(x_inits[3 * agent + 2]);
    float c  = conc(x, y);

    // Register state (was split across two waves + LDS):
    v2f RA[16], RB[16];          // ages 0-15 partial ring (consumer)
    v2f PA[20], PB[20];          // ages 16-31 partial ring (producer)
    float plA[16], plB[16];      // shipped partial_1 ring (was part1 LDS)
    v2f eA_xy[4], eA_zc[4];      // state buffers (was es + e4buf)
    v2f eB_xy[4], eB_zc[4];
    float S_c = 0.f, S_u = 0.f;

    {   // seeds — both waves' seeds, verbatim (producer ages at +16)
        v2f exy0 = {x, y}, ezc0 = {th, c};
        {   v2f aA = {0.f,0.f}, aB = {0.f,0.f};
            #pragma unroll
            for (int k = 15; k >= 0; --k) {
                aA = WxyA[k]*exy0 + aA;  aA = WzcA[k]*ezc0 + aA;
                aB = WxyB[k]*exy0 + aB;  aB = WzcB[k]*ezc0 + aB;
                RA[k] = aA;  RB[k] = aB;
            }
        }
        #pragma unroll
        for (int i = 15; i < 20; ++i) { PA[i] = (v2f){0.f,0.f}; PB[i] = (v2f){0.f,0.f}; }
        {   v2f aA = {0.f,0.f}, aB = {0.f,0.f};
            #pragma unroll
            for (int k = 15; k >= 1; --k) {
                aA = WxyA[16+k]*exy0 + aA;  aA = WzcA[16+k]*ezc0 + aA;
                aB = WxyB[16+k]*exy0 + aB;  aB = WzcB[16+k]*ezc0 + aB;
                PA[k-1] = aA;  PB[k-1] = aB;
            }
            v2f fA = WxyA[16]*exy0 + aA;  fA = WzcA[16]*ezc0 + fA;
            v2f fB = WxyB[16]*exy0 + aB;  fB = WzcB[16]*ezc0 + fB;
            float fullA = fA.x + fA.y, fullB = fB.x + fB.y;
            #pragma unroll
            for (int s = 0; s <= 8; ++s) { plA[s] = fullA; plB[s] = fullB; }
        }
        #pragma unroll
        for (int i = 0; i < 4; ++i) { eB_xy[i] = exy0; eB_zc[i] = ezc0; }
        // plA[9..15]: 9-12 filled by prologue h1(n=0); 13-15 by the first
        // in-loop h1(n=1) before steps 13-15 consume them.
    }

    // producer batch, verbatim R27 form (overwrite-first), ages at +16
    auto h1_batch = [&](v2f (&px)[4], v2f (&pz)[4], int n) {
        #pragma unroll
        for (int kk = 0; kk < 16; ++kk) {
            #pragma unroll
            for (int i = 0; i < 4; ++i) {
                const int idx = i + kk;
                if (i == 3 && kk >= 12) {
                    PA[idx] = WxyA[16+kk]*px[i];
                    PA[idx] = WzcA[16+kk]*pz[i] + PA[idx];
                    PB[idx] = WxyB[16+kk]*px[i];
                    PB[idx] = WzcB[16+kk]*pz[i] + PB[idx];
                } else {
                    PA[idx] = WxyA[16+kk]*px[i] + PA[idx];
                    PA[idx] = WzcA[16+kk]*pz[i] + PA[idx];
                    PB[idx] = WxyB[16+kk]*px[i] + PB[idx];
                    PB[idx] = WzcB[16+kk]*pz[i] + PB[idx];
                }
            }
        }
        #pragma unroll
        for (int i = 0; i < 4; ++i) {
            plA[(9 + 4*n + i) & 15] = PA[i].x + PA[i].y;
            plB[(9 + 4*n + i) & 15] = PB[i].x + PB[i].y;
        }
        #pragma unroll
        for (int i = 0; i < 16; ++i) { PA[i] = PA[i+4]; PB[i] = PB[i+4]; }
    };

    // prologue h1(0,0): inputs e0 x4 (eB), ships pl[9..12]
    h1_batch(eB_xy, eB_zc, 0);

    auto h0_step = [&](int j, v2f (&bx)[4], v2f (&bz)[4]) {
        float hA = fmaxf((RA[j & 15].x + RA[j & 15].y) + plA[j & 15] + b1A, 0.f);
        float hB = fmaxf((RB[j & 15].x + RB[j & 15].y) + plB[j & 15] + b1B, 0.f);
        float r0 = fmaf(w20A, hA, w20B * hB);
        float r1 = fmaf(w21A, hA, w21B * hB);
        wave_sum2_dpp(r0, r1);
        float s0 = __builtin_bit_cast(float,
            __builtin_amdgcn_readlane(__builtin_bit_cast(int, r0), 63));
        float s1 = __builtin_bit_cast(float,
            __builtin_amdgcn_readlane(__builtin_bit_cast(int, r1), 63));
        float v  = tanh_fast(s0 + b2x);
        float wv = tanh_fast(s1 + b2y);
        S_u += v * v + wv * wv;
        float sn = __sinf(th), cs = __cosf(th);
        float dv = DT * v;
        x  = fmaf(dv, cs, x);
        y  = fmaf(dv, sn, y);
        th = fmaf(DT, wv, th);
        c  = conc(x, y);
        S_c += c;
        v2f exy = {x, y}, ezc = {th, c};
        bx[j & 3] = exy;  bz[j & 3] = ezc;
        // urgent taps: k <= 2 - (j&3)
        #pragma unroll
        for (int k = 0; k < 3; ++k) {
            if (k <= 2 - (j & 3)) {
                const int m = (j + 1 + k) & 15;
                RA[m] = WxyA[k]*exy + RA[m];  RA[m] = WzcA[k]*ezc + RA[m];
                RB[m] = WxyB[k]*exy + RB[m];  RB[m] = WzcB[k]*ezc + RB[m];
            }
        }
    };
    auto h0_batch = [&](int q, v2f (&bx)[4], v2f (&bz)[4]) {
        #pragma unroll
        for (int kk = 0; kk < 16; ++kk) {
            #pragma unroll
            for (int i = 0; i < 4; ++i) {
                if (kk >= 3 - i) {
                    const int m = (4*q + i + 1 + kk) & 15;
                    if (i == 3 && kk >= 12) {
                        RA[m] = WxyA[kk]*bx[i];
                        RA[m] = WzcA[kk]*bz[i] + RA[m];
                        RB[m] = WxyB[kk]*bx[i];
                        RB[m] = WzcB[kk]*bz[i] + RB[m];
                    } else {
                        RA[m] = WxyA[kk]*bx[i] + RA[m];
                        RA[m] = WzcA[kk]*bz[i] + RA[m];
                        RB[m] = WxyB[kk]*bx[i] + RB[m];
                        RB[m] = WzcB[kk]*bz[i] + RB[m];
                    }
                }
            }
        }
    };

    #pragma unroll 1
    for (int b = 0; b < 62; ++b) {
        // group 0: steps 0-3 -> eA
        h0_step(0, eA_xy, eA_zc);  h0_step(1, eA_xy, eA_zc);
        h0_step(2, eA_xy, eA_zc);  h0_step(3, eA_xy, eA_zc);
        h0_batch(0, eA_xy, eA_zc);
        h1_batch(eB_xy, eB_zc, 1);          // inputs: prev window grp 3 (or e0)
        // group 1: steps 4-7 -> eB
        h0_step(4, eB_xy, eB_zc);  h0_step(5, eB_xy, eB_zc);
        h0_step(6, eB_xy, eB_zc);  h0_step(7, eB_xy, eB_zc);
        h0_batch(1, eB_xy, eB_zc);
        h1_batch(eA_xy, eA_zc, 2);          // inputs: this window grp 0
        // group 2: steps 8-11 -> eA
        h0_step(8, eA_xy, eA_zc);   h0_step(9, eA_xy, eA_zc);
        h0_step(10, eA_xy, eA_zc);  h0_step(11, eA_xy, eA_zc);
        h0_batch(2, eA_xy, eA_zc);
        h1_batch(eB_xy, eB_zc, 3);          // inputs: this window grp 1
        // group 3: steps 12-15 -> eB
        h0_step(12, eB_xy, eB_zc);  h0_step(13, eB_xy, eB_zc);
        h0_step(14, eB_xy, eB_zc);  h0_step(15, eB_xy, eB_zc);
        h0_batch(3, eB_xy, eB_zc);
        h1_batch(eA_xy, eA_zc, 0);          // inputs: this window grp 2
    }
    // remainder: steps 992..999 (window 62 rel 0-7); pl[0..7] shipped
    // during window 61; h1 outputs would never be consumed -> skipped.
    h0_step(0, eA_xy, eA_zc);  h0_step(1, eA_xy, eA_zc);
    h0_step(2, eA_xy, eA_zc);  h0_step(3, eA_xy, eA_zc);
    h0_batch(0, eA_xy, eA_zc);
    h0_step(4, eB_xy, eB_zc);  h0_step(5, eB_xy, eB_zc);
    h0_step(6, eB_xy, eB_zc);  h0_step(7, eB_xy, eB_zc);

    if (lane == 0) ws[agent] = make_float2(S_c, S_u);
}

__global__ void reduce_kernel(const float2* __restrict__ ws,
                              float* __restrict__ out) {
    const int tid = threadIdx.x;  // 256 threads
    float sc = 0.f, su = 0.f;
    for (int i = tid; i < N_AGENTS; i += 256) {
        float2 v = ws[i];
        sc += v.x;
        su += v.y;
    }
    #pragma unroll
    for (int off = 32; off > 0; off >>= 1) {
        sc += __shfl_xor(sc, off);
        su += __shfl_xor(su, off);
    }
    __shared__ float2 partw[4];
    int wave = tid >> 6;
    if ((tid & 63) == 0) partw[wave] = make_float2(sc, su);
    __syncthreads();
    if (tid == 0) {
        float SC = partw[0].x + partw[1].x + partw[2].x + partw[3].x;
        float SU = partw[0].y + partw[1].y + partw[2].y + partw[3].y;
        const float invNT  = 1.0f / (float)(N_AGENTS * T_STEPS);
        const float invNT2 = 1.0f / (float)(N_AGENTS * T_STEPS * 2);
        out[0] = -SC * invNT + SU * invNT2;
    }
}

extern "C" void kernel_launch(void* const* d_in, const int* in_sizes, int n_in,
                              void* d_out, int out_size, void* d_ws, size_t ws_size,
                              hipStream_t stream) {
    const float* target_pos = (const float*)d_in[0];
    const float* logsigma   = (const float*)d_in[1];
    const float* x_inits    = (const float*)d_in[2];
    const float* W1         = (const float*)d_in[3];
    const float* b1         = (const float*)d_in[4];
    const float* W2         = (const float*)d_in[5];
    const float* b2         = (const float*)d_in[6];

    float*  pw   = (float*)d_ws;                          // 64 KB packed W1
    float2* sums = (float2*)((char*)d_ws + 64 * 1024);    // per-agent sums

    pack_kernel<<<HIDDEN, 32, 0, stream>>>(W1, pw);
    sim_kernel<<<N_AGENTS, 64, 0, stream>>>(target_pos, logsigma, x_inits,
                                            pw, b1, W2, b2, sums);
    reduce_kernel<<<1, 256, 0, stream>>>(sums, (float*)d_out);
}